// Round 7
// baseline (331.148 us; speedup 1.0000x reference)
//
#include <hip/hip_runtime.h>

typedef _Float16 f16;
typedef _Float16 f16x8 __attribute__((ext_vector_type(8)));
typedef float f32x4 __attribute__((ext_vector_type(4)));

#define GLOBAL_AS __attribute__((address_space(1)))
#define LDS_AS __attribute__((address_space(3)))

__device__ __forceinline__ void async16(const void* g, void* l) {
  __builtin_amdgcn_global_load_lds((const GLOBAL_AS unsigned int*)g,
                                   (LDS_AS unsigned int*)l, 16, 0, 0);
}

// ---------------- merged conversion kernel ----------------
// blocks [0,12800):       spikes fp32 [32768][784] -> A16 f16 [32768][800] (pad)
// blocks [12800,16256):   w_hidden -> w2h (hi|lo*2048, padded); w_out -> w2o (hi)
__global__ __launch_bounds__(256) void conv_all(const float* __restrict__ s,
                                                const float* __restrict__ wh,
                                                const float* __restrict__ wo,
                                                f16* __restrict__ a16,
                                                f16* __restrict__ w2h,
                                                f16* __restrict__ w2o) {
  if (blockIdx.x < 12800) {
    int idx = blockIdx.x * 256 + threadIdx.x;  // < 3,276,800
    int m = idx / 100;
    int g = idx - m * 100;
    f16x8 h = {};
    if (g < 98) {
      const float4* p = (const float4*)(s + (size_t)m * 784 + g * 8);
      float4 x = p[0];
      float4 y = p[1];
      h[0] = (f16)x.x; h[1] = (f16)x.y; h[2] = (f16)x.z; h[3] = (f16)x.w;
      h[4] = (f16)y.x; h[5] = (f16)y.y; h[6] = (f16)y.z; h[7] = (f16)y.w;
    }
    *(f16x8*)(a16 + (size_t)m * 800 + g * 8) = h;
  } else {
    int idx = (blockIdx.x - 12800) * 256 + threadIdx.x;
    if (idx < 819200) {
      int h = idx / 1600;
      int c = idx - h * 1600;
      f16 o = (f16)0.f;
      if (c < 784) {
        o = (f16)wh[h * 784 + c];
      } else if (c >= 800 && c < 1584) {
        float x = wh[h * 784 + (c - 800)];
        f16 hi = (f16)x;
        o = (f16)((x - (float)hi) * 2048.0f);  // exact residual, scaled past denormals
      }
      w2h[idx] = o;
    } else if (idx < 819200 + 65536) {
      int j = idx - 819200;
      w2o[j] = (f16)wo[j];
    }
  }
}

// ---------------- f16 MFMA GEMM, BK=64, XOR-swizzled LDS (R4-proven) ----------------
// C[M][N_LD] = A[M][K] * B[N][K]^T (+ 2^-11 * A*B_lo^T if B_OFF_LO>0).
// LDS: row r holds its 8 16B-granules permuted p = g ^ (r&7): a quad's 16-row
// ds_read_b128 sweep hits all 32 banks (2 lanes/bank = free).
// XCD_SWZ: 1-D grid of 4*256 blocks, mapped so the 4 n-blocks of one m-tile
// land on the same XCD (A rows read once per XCD L2).
// __launch_bounds__(256,3): 3 blocks/CU (LDS 3x48=144<=160 KB, VGPR<=170) for
// latency overlap across co-resident blocks — this kernel is drain-bound.
template <int N_LD, int A_STRIDE, int B_STRIDE, int NCH64, bool TAIL32,
          int B_OFF_LO, int KSPLIT_SPAN, bool XCD_SWZ>
__global__ __launch_bounds__(256, 3) void gemm_f16(const f16* __restrict__ A,
                                                   const f16* __restrict__ B,
                                                   float* __restrict__ C) {
  constexpr bool HAS_LO = (B_OFF_LO > 0);
  __shared__ f16 lds_a[128 * 64];
  __shared__ f16 lds_bh[128 * 64];
  __shared__ f16 lds_bl[HAS_LO ? 128 * 64 : 8];
  const int t = threadIdx.x;
  const int lane = t & 63;
  const int wave = t >> 6;
  int bx, by;
  if (XCD_SWZ) {
    const int b = blockIdx.x;
    by = (b & 7) + 8 * (b >> 5);
    bx = (b >> 3) & 3;
  } else {
    bx = blockIdx.x;
    by = blockIdx.y;
  }
  const int m0 = by * 128;
  const int n0 = KSPLIT_SPAN ? 0 : bx * 128;
  const int kb = KSPLIT_SPAN ? bx * KSPLIT_SPAN : 0;
  float* Cp = KSPLIT_SPAN ? C + (size_t)bx * 32768 * N_LD : C;
  const int wm = (wave >> 1) * 64;
  const int wn = (wave & 1) * 64;
  const int row = lane & 15;
  const int quad = lane >> 4;

  f32x4 acch[4][4] = {};
  f32x4 accl[HAS_LO ? 4 : 1][4] = {};

  for (int c = 0; c < NCH64; ++c) {
    const int k0 = kb + c * 64;
#pragma unroll
    for (int s = 0; s < 4; ++s) {
      const int j = t + s * 256;
      const int r = j >> 3;
      const int g = (j & 7) ^ (r & 7);  // xor-swizzled source granule
      async16(A + (m0 + r) * A_STRIDE + k0 + g * 8, &lds_a[j * 8]);
      async16(B + (n0 + r) * B_STRIDE + k0 + g * 8, &lds_bh[j * 8]);
      if (HAS_LO)
        async16(B + (n0 + r) * B_STRIDE + B_OFF_LO + k0 + g * 8, &lds_bl[j * 8]);
    }
    __syncthreads();
#pragma unroll
    for (int ks = 0; ks < 2; ++ks) {
      f16x8 af[4], bh[4], bl[4];
#pragma unroll
      for (int tm = 0; tm < 4; ++tm) {
        const int ra = wm + tm * 16 + row;
        const int p = (ks * 4 + quad) ^ (ra & 7);
        af[tm] = *(const f16x8*)&lds_a[ra * 64 + p * 8];
      }
#pragma unroll
      for (int tn = 0; tn < 4; ++tn) {
        const int rb = wn + tn * 16 + row;
        const int p = (ks * 4 + quad) ^ (rb & 7);
        bh[tn] = *(const f16x8*)&lds_bh[rb * 64 + p * 8];
        if (HAS_LO) bl[tn] = *(const f16x8*)&lds_bl[rb * 64 + p * 8];
      }
#pragma unroll
      for (int tm = 0; tm < 4; ++tm)
#pragma unroll
        for (int tn = 0; tn < 4; ++tn) {
          acch[tm][tn] =
              __builtin_amdgcn_mfma_f32_16x16x32_f16(af[tm], bh[tn], acch[tm][tn], 0, 0, 0);
          if (HAS_LO)
            accl[tm][tn] =
                __builtin_amdgcn_mfma_f32_16x16x32_f16(af[tm], bl[tn], accl[tm][tn], 0, 0, 0);
        }
    }
    __syncthreads();
  }

  if (TAIL32) {  // one 32-wide K tail chunk; rows have 4 granules, swizzle &3
    const int k0 = kb + NCH64 * 64;
#pragma unroll
    for (int s = 0; s < 2; ++s) {
      const int j = t + s * 256;
      const int r = j >> 2;
      const int g = (j & 3) ^ (r & 3);
      async16(A + (m0 + r) * A_STRIDE + k0 + g * 8, &lds_a[j * 8]);
      async16(B + (n0 + r) * B_STRIDE + k0 + g * 8, &lds_bh[j * 8]);
      if (HAS_LO)
        async16(B + (n0 + r) * B_STRIDE + B_OFF_LO + k0 + g * 8, &lds_bl[j * 8]);
    }
    __syncthreads();
    f16x8 af[4], bh[4], bl[4];
#pragma unroll
    for (int tm = 0; tm < 4; ++tm) {
      const int ra = wm + tm * 16 + row;
      const int p = quad ^ (ra & 3);
      af[tm] = *(const f16x8*)&lds_a[ra * 32 + p * 8];
    }
#pragma unroll
    for (int tn = 0; tn < 4; ++tn) {
      const int rb = wn + tn * 16 + row;
      const int p = quad ^ (rb & 3);
      bh[tn] = *(const f16x8*)&lds_bh[rb * 32 + p * 8];
      if (HAS_LO) bl[tn] = *(const f16x8*)&lds_bl[rb * 32 + p * 8];
    }
#pragma unroll
    for (int tm = 0; tm < 4; ++tm)
#pragma unroll
      for (int tn = 0; tn < 4; ++tn) {
        acch[tm][tn] =
            __builtin_amdgcn_mfma_f32_16x16x32_f16(af[tm], bh[tn], acch[tm][tn], 0, 0, 0);
        if (HAS_LO)
          accl[tm][tn] =
              __builtin_amdgcn_mfma_f32_16x16x32_f16(af[tm], bl[tn], accl[tm][tn], 0, 0, 0);
      }
  }

  // C/D layout: col = lane&15, row = quad*4 + r
#pragma unroll
  for (int tm = 0; tm < 4; ++tm)
#pragma unroll
    for (int tn = 0; tn < 4; ++tn)
#pragma unroll
      for (int r = 0; r < 4; ++r) {
        const int mm = m0 + wm + tm * 16 + quad * 4 + r;
        const int nn = n0 + wn + tn * 16 + row;
        float val = acch[tm][tn][r];
        if (HAS_LO) val += 4.8828125e-4f * accl[tm][tn][r];  // 2^-11 exact
        Cp[(size_t)mm * N_LD + nn] = val;
      }
}

// ---------------- CUBA LIF scan (double-buffered batches of 8) ----------------
__global__ __launch_bounds__(256) void lif_scan(const float* __restrict__ ch,
                                                f16* __restrict__ sh) {
  const int n = blockIdx.x * 256 + threadIdx.x;  // 65536 neurons
  float xa[8], xb[8];
#pragma unroll
  for (int j = 0; j < 8; ++j) xa[j] = ch[j * 65536 + n];
  float v = 0.f, cur = 0.f;
  for (int c = 0; c < 32; ++c) {
    const int nc = (c + 1) & 31;  // wrap: chunk-0 reload at c=31 is dead, L2-hot
#pragma unroll
    for (int j = 0; j < 8; ++j) xb[j] = ch[(nc * 8 + j) * 65536 + n];
#pragma unroll
    for (int j = 0; j < 8; ++j) {
      const int t = c * 8 + j;
      float x = xa[j];
      v = v + 0.16666667f * (cur - v);  // v += dt*tau_mem_inv*(-v+i), old i
      cur = 0.8333333f * cur + x;       // i = i*(1-dt*tau_syn_inv) + x
      bool z = v > 1.0f;
      sh[t * 65536 + n] = z ? (f16)1.f : (f16)0.f;
      v = z ? 0.f : v;
    }
#pragma unroll
    for (int j = 0; j < 8; ++j) xa[j] = xb[j];
  }
}

// ---------------- CUBA LI scan, 4-way T-segmented ----------------
// LI is linear; state decays (5/6)^d. Segments warm-run the previous 64 steps
// from zero state (err < 4e-3 rel), then emit 64 outputs. Sums K-split streams.
__global__ __launch_bounds__(256) void li_scan_seg(const float* __restrict__ coA,
                                                   const float* __restrict__ coB,
                                                   float* __restrict__ out) {
  const int tid = blockIdx.x * 256 + threadIdx.x;  // 65536
  const int n = tid & 16383;
  const int seg = tid >> 14;  // 0..3
  const int t0 = seg * 64;
  float v = 0.f, cur = 0.f;
  float xa[8], xb[8];
  if (seg) {
    const int w0 = t0 - 64;
#pragma unroll
    for (int j = 0; j < 8; ++j)
      xa[j] = coA[(w0 + j) * 16384 + n] + coB[(w0 + j) * 16384 + n];
    for (int c = 0; c < 8; ++c) {
      const int nb = w0 + (c + 1) * 8;  // c==7 prefetches t0..t0+7
#pragma unroll
      for (int j = 0; j < 8; ++j)
        xb[j] = coA[(nb + j) * 16384 + n] + coB[(nb + j) * 16384 + n];
#pragma unroll
      for (int j = 0; j < 8; ++j) {
        v = v + 0.16666667f * (cur - v);
        cur = 0.8333333f * cur + xa[j];
      }
#pragma unroll
      for (int j = 0; j < 8; ++j) xa[j] = xb[j];
    }
  } else {
#pragma unroll
    for (int j = 0; j < 8; ++j) xa[j] = coA[j * 16384 + n] + coB[j * 16384 + n];
  }
  for (int c = 0; c < 8; ++c) {
    if (c < 7) {
      const int nb = t0 + (c + 1) * 8;
#pragma unroll
      for (int j = 0; j < 8; ++j)
        xb[j] = coA[(nb + j) * 16384 + n] + coB[(nb + j) * 16384 + n];
    }
#pragma unroll
    for (int j = 0; j < 8; ++j) {
      const int t = t0 + c * 8 + j;
      v = v + 0.16666667f * (cur - v);
      cur = 0.8333333f * cur + xa[j];
      out[t * 16384 + n] = v;
    }
#pragma unroll
    for (int j = 0; j < 8; ++j) xa[j] = xb[j];
  }
}

// ---------------- launch ----------------
extern "C" void kernel_launch(void* const* d_in, const int* in_sizes, int n_in,
                              void* d_out, int out_size, void* d_ws, size_t ws_size,
                              hipStream_t stream) {
  const float* spikes = (const float*)d_in[0];    // [256][128][784]
  const float* w_hidden = (const float*)d_in[1];  // [512][784]
  const float* w_out = (const float*)d_in[2];     // [128][512]
  float* out = (float*)d_out;                     // [256][128][128]

  char* ws = (char*)d_ws;
  // layout (bytes):
  //   A16  [32768][800] f16 : 52,428,800  (later aliased by coA|coB, 2x16,777,216)
  //   w2h  [512][1600]  f16 :  1,638,400
  //   c_h  [32768][512] f32 : 67,108,864
  //   s_h  [32768][512] f16 : 33,554,432
  //   w2o  [128][512]   f16 :    131,072
  f16* A16 = (f16*)ws;
  float* coA = (float*)ws;  // alias: A16 dead after GEMM1
  float* coB = (float*)(ws + 16777216);
  f16* w2h = (f16*)(ws + 52428800);
  float* c_h = (float*)(ws + 52428800 + 1638400);
  f16* s_h = (f16*)(ws + 52428800 + 1638400 + 67108864);
  f16* w2o = (f16*)(ws + 52428800 + 1638400 + 67108864 + 33554432);

  // merged conversions: spikes->A16 and weights->w2h/w2o in one dispatch
  conv_all<<<16256, 256, 0, stream>>>(spikes, w_hidden, w_out, A16, w2h, w2o);

  // GEMM1: c_h[32768][512] = A16[32768][800] * w2h[512][800hi|800lo]^T, K=12*64+32
  // 1-D grid, XCD-swizzled so the 4 n-blocks of an m-tile share an XCD's L2.
  gemm_f16<512, 800, 1600, 12, true, 800, 0, true>
      <<<1024, 256, 0, stream>>>(A16, w2h, c_h);

  lif_scan<<<256, 256, 0, stream>>>(c_h, s_h);

  // GEMM2: co{A,B}[32768][128] = s_h[32768][512] * w2o[128][512]^T, K-split 2x256
  gemm_f16<128, 512, 512, 4, false, 0, 256, false>
      <<<dim3(2, 256), 256, 0, stream>>>(s_h, w2o, coA);

  li_scan_seg<<<256, 256, 0, stream>>>(coA, coB, out);
}

// Round 9
// 248.437 us; speedup vs baseline: 1.3329x; 1.3329x over previous
//
#include <hip/hip_runtime.h>

typedef _Float16 f16;
typedef _Float16 f16x8 __attribute__((ext_vector_type(8)));
typedef float f32x4 __attribute__((ext_vector_type(4)));

#define GLOBAL_AS __attribute__((address_space(1)))
#define LDS_AS __attribute__((address_space(3)))

// async global->LDS. LESSON (R8): LDS dest = wave-uniform base + lane*16 —
// NEVER issue this under potentially-divergent control flow or with per-lane
// conditional addressing; R8's tail ternary caused schedule-dependent LDS
// corruption (passed once, diverged under graph replay).
__device__ __forceinline__ void async16(const void* g, void* l) {
  __builtin_amdgcn_global_load_lds((const GLOBAL_AS unsigned int*)g,
                                   (LDS_AS unsigned int*)l, 16, 0, 0);
}

// ---------------- merged conversion kernel (R7-proven) ----------------
// blocks [0,12800):     spikes fp32 [32768][784] -> A16 f16 [32768][800] (pad 0)
// blocks [12800,16256): w_hidden -> w2h (hi pad->800 | lo*2048 pad->1600); w_out -> w2o
__global__ __launch_bounds__(256) void conv_all(const float* __restrict__ s,
                                                const float* __restrict__ wh,
                                                const float* __restrict__ wo,
                                                f16* __restrict__ a16,
                                                f16* __restrict__ w2h,
                                                f16* __restrict__ w2o) {
  if (blockIdx.x < 12800) {
    int idx = blockIdx.x * 256 + threadIdx.x;  // < 3,276,800
    int m = idx / 100;
    int g = idx - m * 100;
    f16x8 h = {};
    if (g < 98) {
      const float4* p = (const float4*)(s + (size_t)m * 784 + g * 8);
      float4 x = p[0];
      float4 y = p[1];
      h[0] = (f16)x.x; h[1] = (f16)x.y; h[2] = (f16)x.z; h[3] = (f16)x.w;
      h[4] = (f16)y.x; h[5] = (f16)y.y; h[6] = (f16)y.z; h[7] = (f16)y.w;
    }
    *(f16x8*)(a16 + (size_t)m * 800 + g * 8) = h;
  } else {
    int idx = (blockIdx.x - 12800) * 256 + threadIdx.x;
    if (idx < 819200) {
      int h = idx / 1600;
      int c = idx - h * 1600;
      f16 o = (f16)0.f;
      if (c < 784) {
        o = (f16)wh[h * 784 + c];
      } else if (c >= 800 && c < 1584) {
        float x = wh[h * 784 + (c - 800)];
        f16 hi = (f16)x;
        o = (f16)((x - (float)hi) * 2048.0f);  // exact residual, scaled past denormals
      }
      w2h[idx] = o;
    } else if (idx < 819200 + 65536) {
      int j = idx - 819200;
      w2o[j] = (f16)wo[j];
    }
  }
}

// ---------------- f16 MFMA GEMM, BK=64, XOR-swizzled LDS (R4-proven) ----------------
// C[M][N_LD] = A[M][K] * B[N][K]^T (+ 2^-11 * A*B_lo^T if B_OFF_LO>0).
// LDS: row r holds its 8 16B-granules permuted p = g ^ (r&7): a quad's 16-row
// ds_read_b128 sweep hits all 32 banks (2 lanes/bank = free; R3->R4 fixed 14.3M
// conflicts). XCD_SWZ: 1-D grid of 4*256 blocks, mapped so the 4 n-blocks of an
// m-tile share an XCD's L2.
// __launch_bounds__(256,2) ONLY: (256,3) caps VGPR at 84 and spills the 128-VGPR
// accumulator to scratch (R7: 137 us, WRITE_SIZE +46 MB). Needs ~150 VGPRs.
template <int N_LD, int A_STRIDE, int B_STRIDE, int NCH64, bool TAIL32,
          int B_OFF_LO, int KSPLIT_SPAN, bool XCD_SWZ>
__global__ __launch_bounds__(256, 2) void gemm_f16(const f16* __restrict__ A,
                                                   const f16* __restrict__ B,
                                                   float* __restrict__ C) {
  constexpr bool HAS_LO = (B_OFF_LO > 0);
  __shared__ __align__(16) f16 lds_a[128 * 64];
  __shared__ __align__(16) f16 lds_bh[128 * 64];
  __shared__ __align__(16) f16 lds_bl[HAS_LO ? 128 * 64 : 8];
  const int t = threadIdx.x;
  const int lane = t & 63;
  const int wave = t >> 6;
  int bx, by;
  if (XCD_SWZ) {
    const int b = blockIdx.x;
    by = (b & 7) + 8 * (b >> 5);
    bx = (b >> 3) & 3;
  } else {
    bx = blockIdx.x;
    by = blockIdx.y;
  }
  const int m0 = by * 128;
  const int n0 = KSPLIT_SPAN ? 0 : bx * 128;
  const int kb = KSPLIT_SPAN ? bx * KSPLIT_SPAN : 0;
  float* Cp = KSPLIT_SPAN ? C + (size_t)bx * 32768 * N_LD : C;
  const int wm = (wave >> 1) * 64;
  const int wn = (wave & 1) * 64;
  const int row = lane & 15;
  const int quad = lane >> 4;

  f32x4 acch[4][4] = {};
  f32x4 accl[HAS_LO ? 4 : 1][4] = {};

  for (int c = 0; c < NCH64; ++c) {
    const int k0 = kb + c * 64;
#pragma unroll
    for (int s = 0; s < 4; ++s) {
      const int j = t + s * 256;
      const int r = j >> 3;
      const int g = (j & 7) ^ (r & 7);  // xor-swizzled source granule
      async16(A + (m0 + r) * A_STRIDE + k0 + g * 8, &lds_a[j * 8]);
      async16(B + (n0 + r) * B_STRIDE + k0 + g * 8, &lds_bh[j * 8]);
      if (HAS_LO)
        async16(B + (n0 + r) * B_STRIDE + B_OFF_LO + k0 + g * 8, &lds_bl[j * 8]);
    }
    __syncthreads();
#pragma unroll
    for (int ks = 0; ks < 2; ++ks) {
      f16x8 af[4], bh[4], bl[4];
#pragma unroll
      for (int tm = 0; tm < 4; ++tm) {
        const int ra = wm + tm * 16 + row;
        const int p = (ks * 4 + quad) ^ (ra & 7);
        af[tm] = *(const f16x8*)&lds_a[ra * 64 + p * 8];
      }
#pragma unroll
      for (int tn = 0; tn < 4; ++tn) {
        const int rb = wn + tn * 16 + row;
        const int p = (ks * 4 + quad) ^ (rb & 7);
        bh[tn] = *(const f16x8*)&lds_bh[rb * 64 + p * 8];
        if (HAS_LO) bl[tn] = *(const f16x8*)&lds_bl[rb * 64 + p * 8];
      }
#pragma unroll
      for (int tm = 0; tm < 4; ++tm)
#pragma unroll
        for (int tn = 0; tn < 4; ++tn) {
          acch[tm][tn] =
              __builtin_amdgcn_mfma_f32_16x16x32_f16(af[tm], bh[tn], acch[tm][tn], 0, 0, 0);
          if (HAS_LO)
            accl[tm][tn] =
                __builtin_amdgcn_mfma_f32_16x16x32_f16(af[tm], bl[tn], accl[tm][tn], 0, 0, 0);
        }
    }
    __syncthreads();
  }

  if (TAIL32) {  // one 32-wide K tail chunk; rows have 4 granules, swizzle &3
    const int k0 = kb + NCH64 * 64;
#pragma unroll
    for (int s = 0; s < 2; ++s) {
      const int j = t + s * 256;
      const int r = j >> 2;
      const int g = (j & 3) ^ (r & 3);
      async16(A + (m0 + r) * A_STRIDE + k0 + g * 8, &lds_a[j * 8]);
      async16(B + (n0 + r) * B_STRIDE + k0 + g * 8, &lds_bh[j * 8]);
      if (HAS_LO)
        async16(B + (n0 + r) * B_STRIDE + B_OFF_LO + k0 + g * 8, &lds_bl[j * 8]);
    }
    __syncthreads();
    f16x8 af[4], bh[4], bl[4];
#pragma unroll
    for (int tm = 0; tm < 4; ++tm) {
      const int ra = wm + tm * 16 + row;
      const int p = quad ^ (ra & 3);
      af[tm] = *(const f16x8*)&lds_a[ra * 32 + p * 8];
    }
#pragma unroll
    for (int tn = 0; tn < 4; ++tn) {
      const int rb = wn + tn * 16 + row;
      const int p = quad ^ (rb & 3);
      bh[tn] = *(const f16x8*)&lds_bh[rb * 32 + p * 8];
      if (HAS_LO) bl[tn] = *(const f16x8*)&lds_bl[rb * 32 + p * 8];
    }
#pragma unroll
    for (int tm = 0; tm < 4; ++tm)
#pragma unroll
      for (int tn = 0; tn < 4; ++tn) {
        acch[tm][tn] =
            __builtin_amdgcn_mfma_f32_16x16x32_f16(af[tm], bh[tn], acch[tm][tn], 0, 0, 0);
        if (HAS_LO)
          accl[tm][tn] =
              __builtin_amdgcn_mfma_f32_16x16x32_f16(af[tm], bl[tn], accl[tm][tn], 0, 0, 0);
      }
  }

  // C/D layout: col = lane&15, row = quad*4 + r
#pragma unroll
  for (int tm = 0; tm < 4; ++tm)
#pragma unroll
    for (int tn = 0; tn < 4; ++tn)
#pragma unroll
      for (int r = 0; r < 4; ++r) {
        const int mm = m0 + wm + tm * 16 + quad * 4 + r;
        const int nn = n0 + wn + tn * 16 + row;
        float val = acch[tm][tn][r];
        if (HAS_LO) val += 4.8828125e-4f * accl[tm][tn][r];  // 2^-11 exact
        Cp[(size_t)mm * N_LD + nn] = val;
      }
}

// ---------------- CUBA LIF scan (16-deep double-buffered prefetch) ----------------
// Latency-bound (1 thread/neuron, 4 waves/CU): 16 outstanding loads per thread.
__global__ __launch_bounds__(256) void lif_scan(const float* __restrict__ ch,
                                                f16* __restrict__ sh) {
  const int n = blockIdx.x * 256 + threadIdx.x;  // 65536 neurons
  float xa[16], xb[16];
#pragma unroll
  for (int j = 0; j < 16; ++j) xa[j] = ch[j * 65536 + n];
  float v = 0.f, cur = 0.f;
  for (int c = 0; c < 16; ++c) {
    const int nc = (c + 1) & 15;  // wrap: chunk-0 reload at c=15 is dead, L2-hot
#pragma unroll
    for (int j = 0; j < 16; ++j) xb[j] = ch[(nc * 16 + j) * 65536 + n];
#pragma unroll
    for (int j = 0; j < 16; ++j) {
      const int t = c * 16 + j;
      float x = xa[j];
      v = v + 0.16666667f * (cur - v);  // v += dt*tau_mem_inv*(-v+i), old i
      cur = 0.8333333f * cur + x;       // i = i*(1-dt*tau_syn_inv) + x
      bool z = v > 1.0f;
      sh[t * 65536 + n] = z ? (f16)1.f : (f16)0.f;
      v = z ? 0.f : v;
    }
#pragma unroll
    for (int j = 0; j < 16; ++j) xa[j] = xb[j];
  }
}

// ---------------- CUBA LI scan, 4-way T-segmented (R4-proven) ----------------
// LI is linear; state decays (5/6)^d. Segments warm-run the previous 64 steps
// from zero state (err < 4e-3 rel), then emit 64 outputs. Sums K-split streams.
__global__ __launch_bounds__(256) void li_scan_seg(const float* __restrict__ coA,
                                                   const float* __restrict__ coB,
                                                   float* __restrict__ out) {
  const int tid = blockIdx.x * 256 + threadIdx.x;  // 65536
  const int n = tid & 16383;
  const int seg = tid >> 14;  // 0..3
  const int t0 = seg * 64;
  float v = 0.f, cur = 0.f;
  float xa[8], xb[8];
  if (seg) {
    const int w0 = t0 - 64;
#pragma unroll
    for (int j = 0; j < 8; ++j)
      xa[j] = coA[(w0 + j) * 16384 + n] + coB[(w0 + j) * 16384 + n];
    for (int c = 0; c < 8; ++c) {
      const int nb = w0 + (c + 1) * 8;  // c==7 prefetches t0..t0+7
#pragma unroll
      for (int j = 0; j < 8; ++j)
        xb[j] = coA[(nb + j) * 16384 + n] + coB[(nb + j) * 16384 + n];
#pragma unroll
      for (int j = 0; j < 8; ++j) {
        v = v + 0.16666667f * (cur - v);
        cur = 0.8333333f * cur + xa[j];
      }
#pragma unroll
      for (int j = 0; j < 8; ++j) xa[j] = xb[j];
    }
  } else {
#pragma unroll
    for (int j = 0; j < 8; ++j) xa[j] = coA[j * 16384 + n] + coB[j * 16384 + n];
  }
  for (int c = 0; c < 8; ++c) {
    if (c < 7) {
      const int nb = t0 + (c + 1) * 8;
#pragma unroll
      for (int j = 0; j < 8; ++j)
        xb[j] = coA[(nb + j) * 16384 + n] + coB[(nb + j) * 16384 + n];
    }
#pragma unroll
    for (int j = 0; j < 8; ++j) {
      const int t = t0 + c * 8 + j;
      v = v + 0.16666667f * (cur - v);
      cur = 0.8333333f * cur + xa[j];
      out[t * 16384 + n] = v;
    }
#pragma unroll
    for (int j = 0; j < 8; ++j) xa[j] = xb[j];
  }
}

// ---------------- launch ----------------
extern "C" void kernel_launch(void* const* d_in, const int* in_sizes, int n_in,
                              void* d_out, int out_size, void* d_ws, size_t ws_size,
                              hipStream_t stream) {
  const float* spikes = (const float*)d_in[0];    // [256][128][784]
  const float* w_hidden = (const float*)d_in[1];  // [512][784]
  const float* w_out = (const float*)d_in[2];     // [128][512]
  float* out = (float*)d_out;                     // [256][128][128]

  char* ws = (char*)d_ws;
  // layout (bytes):
  //   A16  [32768][800] f16 : 52,428,800  (later aliased by coA|coB, 2x16,777,216)
  //   w2h  [512][1600]  f16 :  1,638,400
  //   c_h  [32768][512] f32 : 67,108,864
  //   s_h  [32768][512] f16 : 33,554,432
  //   w2o  [128][512]   f16 :    131,072
  f16* A16 = (f16*)ws;
  float* coA = (float*)ws;  // alias: A16 dead after GEMM1
  float* coB = (float*)(ws + 16777216);
  f16* w2h = (f16*)(ws + 52428800);
  float* c_h = (float*)(ws + 52428800 + 1638400);
  f16* s_h = (f16*)(ws + 52428800 + 1638400 + 67108864);
  f16* w2o = (f16*)(ws + 52428800 + 1638400 + 67108864 + 33554432);

  // merged conversions: spikes->A16 and weights->w2h/w2o in one dispatch
  conv_all<<<16256, 256, 0, stream>>>(spikes, w_hidden, w_out, A16, w2h, w2o);

  // GEMM1: c_h[32768][512] = A16[32768][800] * w2h[512][800hi|800lo]^T, K=12*64+32
  gemm_f16<512, 800, 1600, 12, true, 800, 0, true>
      <<<1024, 256, 0, stream>>>(A16, w2h, c_h);

  lif_scan<<<256, 256, 0, stream>>>(c_h, s_h);

  // GEMM2: co{A,B}[32768][128] = s_h[32768][512] * w2o[128][512]^T, K-split 2x256
  gemm_f16<128, 512, 512, 4, false, 0, 256, false>
      <<<dim3(2, 256), 256, 0, stream>>>(s_h, w2o, coA);

  li_scan_seg<<<256, 256, 0, stream>>>(coA, coB, out);
}

// Round 10
// 242.502 us; speedup vs baseline: 1.3656x; 1.0245x over previous
//
#include <hip/hip_runtime.h>

typedef _Float16 f16;
typedef _Float16 f16x8 __attribute__((ext_vector_type(8)));
typedef float f32x4 __attribute__((ext_vector_type(4)));

#define GLOBAL_AS __attribute__((address_space(1)))
#define LDS_AS __attribute__((address_space(3)))

// async global->LDS. LESSON (R8): LDS dest = wave-uniform base + lane*16 —
// NEVER issue under divergent control flow / per-lane conditional addressing
// (schedule-dependent LDS corruption; passed once, diverged under graph replay).
__device__ __forceinline__ void async16(const void* g, void* l) {
  __builtin_amdgcn_global_load_lds((const GLOBAL_AS unsigned int*)g,
                                   (LDS_AS unsigned int*)l, 16, 0, 0);
}

// ---------------- merged conversion kernel (R7/R9-proven) ----------------
// blocks [0,12800):     spikes fp32 [32768][784] -> A16 f16 [32768][800] (pad 0)
// blocks [12800,16256): w_hidden -> w2h (hi pad->800 | lo*2048 pad->1600); w_out -> w2o
__global__ __launch_bounds__(256) void conv_all(const float* __restrict__ s,
                                                const float* __restrict__ wh,
                                                const float* __restrict__ wo,
                                                f16* __restrict__ a16,
                                                f16* __restrict__ w2h,
                                                f16* __restrict__ w2o) {
  if (blockIdx.x < 12800) {
    int idx = blockIdx.x * 256 + threadIdx.x;  // < 3,276,800
    int m = idx / 100;
    int g = idx - m * 100;
    f16x8 h = {};
    if (g < 98) {
      const float4* p = (const float4*)(s + (size_t)m * 784 + g * 8);
      float4 x = p[0];
      float4 y = p[1];
      h[0] = (f16)x.x; h[1] = (f16)x.y; h[2] = (f16)x.z; h[3] = (f16)x.w;
      h[4] = (f16)y.x; h[5] = (f16)y.y; h[6] = (f16)y.z; h[7] = (f16)y.w;
    }
    *(f16x8*)(a16 + (size_t)m * 800 + g * 8) = h;
  } else {
    int idx = (blockIdx.x - 12800) * 256 + threadIdx.x;
    if (idx < 819200) {
      int h = idx / 1600;
      int c = idx - h * 1600;
      f16 o = (f16)0.f;
      if (c < 784) {
        o = (f16)wh[h * 784 + c];
      } else if (c >= 800 && c < 1584) {
        float x = wh[h * 784 + (c - 800)];
        f16 hi = (f16)x;
        o = (f16)((x - (float)hi) * 2048.0f);  // exact residual, scaled past denormals
      }
      w2h[idx] = o;
    } else if (idx < 819200 + 65536) {
      int j = idx - 819200;
      w2o[j] = (f16)wo[j];
    }
  }
}

// ---------------- f16 MFMA GEMM, BK=64, XOR-swizzled LDS (R4/R9-proven) ------------
// C[M][N_LD] = A[M][K] * B[N][K]^T (+ 2^-11 * A*B_lo^T if B_OFF_LO>0), output OUT.
// LDS: row r holds its 8 16B-granules permuted p = g ^ (r&7): a quad's 16-row
// ds_read_b128 sweep hits all 32 banks (2 lanes/bank = free; R3->R4 fixed 14.3M
// conflicts). XCD_SWZ: 1-D grid of 4*256 blocks, the 4 n-blocks of an m-tile on
// one XCD's L2. __launch_bounds__(256,2) ONLY: (256,3) caps VGPR at 84 and
// spills the 128-VGPR accumulator (R7: 137 us, WRITE_SIZE +46 MB).
template <typename OUT, int N_LD, int A_STRIDE, int B_STRIDE, int NCH64,
          bool TAIL32, int B_OFF_LO, int KSPLIT_SPAN, bool XCD_SWZ>
__global__ __launch_bounds__(256, 2) void gemm_f16(const f16* __restrict__ A,
                                                   const f16* __restrict__ B,
                                                   OUT* __restrict__ C) {
  constexpr bool HAS_LO = (B_OFF_LO > 0);
  __shared__ __align__(16) f16 lds_a[128 * 64];
  __shared__ __align__(16) f16 lds_bh[128 * 64];
  __shared__ __align__(16) f16 lds_bl[HAS_LO ? 128 * 64 : 8];
  const int t = threadIdx.x;
  const int lane = t & 63;
  const int wave = t >> 6;
  int bx, by;
  if (XCD_SWZ) {
    const int b = blockIdx.x;
    by = (b & 7) + 8 * (b >> 5);
    bx = (b >> 3) & 3;
  } else {
    bx = blockIdx.x;
    by = blockIdx.y;
  }
  const int m0 = by * 128;
  const int n0 = KSPLIT_SPAN ? 0 : bx * 128;
  const int kb = KSPLIT_SPAN ? bx * KSPLIT_SPAN : 0;
  OUT* Cp = KSPLIT_SPAN ? C + (size_t)bx * 32768 * N_LD : C;
  const int wm = (wave >> 1) * 64;
  const int wn = (wave & 1) * 64;
  const int row = lane & 15;
  const int quad = lane >> 4;

  f32x4 acch[4][4] = {};
  f32x4 accl[HAS_LO ? 4 : 1][4] = {};

  for (int c = 0; c < NCH64; ++c) {
    const int k0 = kb + c * 64;
#pragma unroll
    for (int s = 0; s < 4; ++s) {
      const int j = t + s * 256;
      const int r = j >> 3;
      const int g = (j & 7) ^ (r & 7);  // xor-swizzled source granule
      async16(A + (m0 + r) * A_STRIDE + k0 + g * 8, &lds_a[j * 8]);
      async16(B + (n0 + r) * B_STRIDE + k0 + g * 8, &lds_bh[j * 8]);
      if (HAS_LO)
        async16(B + (n0 + r) * B_STRIDE + B_OFF_LO + k0 + g * 8, &lds_bl[j * 8]);
    }
    __syncthreads();
#pragma unroll
    for (int ks = 0; ks < 2; ++ks) {
      f16x8 af[4], bh[4], bl[4];
#pragma unroll
      for (int tm = 0; tm < 4; ++tm) {
        const int ra = wm + tm * 16 + row;
        const int p = (ks * 4 + quad) ^ (ra & 7);
        af[tm] = *(const f16x8*)&lds_a[ra * 64 + p * 8];
      }
#pragma unroll
      for (int tn = 0; tn < 4; ++tn) {
        const int rb = wn + tn * 16 + row;
        const int p = (ks * 4 + quad) ^ (rb & 7);
        bh[tn] = *(const f16x8*)&lds_bh[rb * 64 + p * 8];
        if (HAS_LO) bl[tn] = *(const f16x8*)&lds_bl[rb * 64 + p * 8];
      }
#pragma unroll
      for (int tm = 0; tm < 4; ++tm)
#pragma unroll
        for (int tn = 0; tn < 4; ++tn) {
          acch[tm][tn] =
              __builtin_amdgcn_mfma_f32_16x16x32_f16(af[tm], bh[tn], acch[tm][tn], 0, 0, 0);
          if (HAS_LO)
            accl[tm][tn] =
                __builtin_amdgcn_mfma_f32_16x16x32_f16(af[tm], bl[tn], accl[tm][tn], 0, 0, 0);
        }
    }
    __syncthreads();
  }

  if (TAIL32) {  // one 32-wide K tail chunk; rows have 4 granules, swizzle &3
    const int k0 = kb + NCH64 * 64;
#pragma unroll
    for (int s = 0; s < 2; ++s) {
      const int j = t + s * 256;
      const int r = j >> 2;
      const int g = (j & 3) ^ (r & 3);
      async16(A + (m0 + r) * A_STRIDE + k0 + g * 8, &lds_a[j * 8]);
      async16(B + (n0 + r) * B_STRIDE + k0 + g * 8, &lds_bh[j * 8]);
      if (HAS_LO)
        async16(B + (n0 + r) * B_STRIDE + B_OFF_LO + k0 + g * 8, &lds_bl[j * 8]);
    }
    __syncthreads();
    f16x8 af[4], bh[4], bl[4];
#pragma unroll
    for (int tm = 0; tm < 4; ++tm) {
      const int ra = wm + tm * 16 + row;
      const int p = quad ^ (ra & 3);
      af[tm] = *(const f16x8*)&lds_a[ra * 32 + p * 8];
    }
#pragma unroll
    for (int tn = 0; tn < 4; ++tn) {
      const int rb = wn + tn * 16 + row;
      const int p = quad ^ (rb & 3);
      bh[tn] = *(const f16x8*)&lds_bh[rb * 32 + p * 8];
      if (HAS_LO) bl[tn] = *(const f16x8*)&lds_bl[rb * 32 + p * 8];
    }
#pragma unroll
    for (int tm = 0; tm < 4; ++tm)
#pragma unroll
      for (int tn = 0; tn < 4; ++tn) {
        acch[tm][tn] =
            __builtin_amdgcn_mfma_f32_16x16x32_f16(af[tm], bh[tn], acch[tm][tn], 0, 0, 0);
        if (HAS_LO)
          accl[tm][tn] =
              __builtin_amdgcn_mfma_f32_16x16x32_f16(af[tm], bl[tn], accl[tm][tn], 0, 0, 0);
      }
  }

  // C/D layout: col = lane&15, row = quad*4 + r
#pragma unroll
  for (int tm = 0; tm < 4; ++tm)
#pragma unroll
    for (int tn = 0; tn < 4; ++tn)
#pragma unroll
      for (int r = 0; r < 4; ++r) {
        const int mm = m0 + wm + tm * 16 + quad * 4 + r;
        const int nn = n0 + wn + tn * 16 + row;
        float val = acch[tm][tn][r];
        if (HAS_LO) val += 4.8828125e-4f * accl[tm][tn][r];  // 2^-11 exact
        Cp[(size_t)mm * N_LD + nn] = (OUT)val;
      }
}

// ---------------- CUBA LIF scan (16-deep prefetch, f16 input) ----------------
// c_h f16: rounding rms ~1.4e-4 rel -> v-err rms ~4.5e-4 -> P(spike shift)~0.5%;
// expected absmax contribution ~0.1 (threshold 0.69). Halves the read traffic.
__global__ __launch_bounds__(256) void lif_scan(const f16* __restrict__ ch,
                                                f16* __restrict__ sh) {
  const int n = blockIdx.x * 256 + threadIdx.x;  // 65536 neurons
  f16 xa[16], xb[16];
#pragma unroll
  for (int j = 0; j < 16; ++j) xa[j] = ch[j * 65536 + n];
  float v = 0.f, cur = 0.f;
  for (int c = 0; c < 16; ++c) {
    const int nc = (c + 1) & 15;  // wrap: chunk-0 reload at c=15 is dead, L2-hot
#pragma unroll
    for (int j = 0; j < 16; ++j) xb[j] = ch[(nc * 16 + j) * 65536 + n];
#pragma unroll
    for (int j = 0; j < 16; ++j) {
      const int t = c * 16 + j;
      float x = (float)xa[j];
      v = v + 0.16666667f * (cur - v);  // v += dt*tau_mem_inv*(-v+i), old i
      cur = 0.8333333f * cur + x;       // i = i*(1-dt*tau_syn_inv) + x
      bool z = v > 1.0f;
      sh[t * 65536 + n] = z ? (f16)1.f : (f16)0.f;
      v = z ? 0.f : v;
    }
#pragma unroll
    for (int j = 0; j < 16; ++j) xa[j] = xb[j];
  }
}

// ---------------- CUBA LI scan, 4-way T-segmented (f16 co inputs) ----------------
// LI is linear; state decays (5/6)^d -> 64-step warm-run error ~1e-4. Sums the
// two K-split co streams (f16: direct out-err ~0.01, no threshold involved).
__global__ __launch_bounds__(256) void li_scan_seg(const f16* __restrict__ coA,
                                                   const f16* __restrict__ coB,
                                                   float* __restrict__ out) {
  const int tid = blockIdx.x * 256 + threadIdx.x;  // 65536
  const int n = tid & 16383;
  const int seg = tid >> 14;  // 0..3
  const int t0 = seg * 64;
  float v = 0.f, cur = 0.f;
  float xa[8], xb[8];
  if (seg) {
    const int w0 = t0 - 64;
#pragma unroll
    for (int j = 0; j < 8; ++j)
      xa[j] = (float)coA[(w0 + j) * 16384 + n] + (float)coB[(w0 + j) * 16384 + n];
    for (int c = 0; c < 8; ++c) {
      const int nb = w0 + (c + 1) * 8;  // c==7 prefetches t0..t0+7
#pragma unroll
      for (int j = 0; j < 8; ++j)
        xb[j] = (float)coA[(nb + j) * 16384 + n] + (float)coB[(nb + j) * 16384 + n];
#pragma unroll
      for (int j = 0; j < 8; ++j) {
        v = v + 0.16666667f * (cur - v);
        cur = 0.8333333f * cur + xa[j];
      }
#pragma unroll
      for (int j = 0; j < 8; ++j) xa[j] = xb[j];
    }
  } else {
#pragma unroll
    for (int j = 0; j < 8; ++j)
      xa[j] = (float)coA[j * 16384 + n] + (float)coB[j * 16384 + n];
  }
  for (int c = 0; c < 8; ++c) {
    if (c < 7) {
      const int nb = t0 + (c + 1) * 8;
#pragma unroll
      for (int j = 0; j < 8; ++j)
        xb[j] = (float)coA[(nb + j) * 16384 + n] + (float)coB[(nb + j) * 16384 + n];
    }
#pragma unroll
    for (int j = 0; j < 8; ++j) {
      const int t = t0 + c * 8 + j;
      v = v + 0.16666667f * (cur - v);
      cur = 0.8333333f * cur + xa[j];
      out[t * 16384 + n] = v;
    }
#pragma unroll
    for (int j = 0; j < 8; ++j) xa[j] = xb[j];
  }
}

// ---------------- launch ----------------
extern "C" void kernel_launch(void* const* d_in, const int* in_sizes, int n_in,
                              void* d_out, int out_size, void* d_ws, size_t ws_size,
                              hipStream_t stream) {
  const float* spikes = (const float*)d_in[0];    // [256][128][784]
  const float* w_hidden = (const float*)d_in[1];  // [512][784]
  const float* w_out = (const float*)d_in[2];     // [128][512]
  float* out = (float*)d_out;                     // [256][128][128]

  char* ws = (char*)d_ws;
  // layout (bytes):
  //   A16  [32768][800] f16 : 52,428,800  (later aliased by coA|coB f16, 2x8,388,608)
  //   w2h  [512][1600]  f16 :  1,638,400
  //   c_h  [32768][512] f16 : 33,554,432
  //   s_h  [32768][512] f16 : 33,554,432
  //   w2o  [128][512]   f16 :    131,072
  f16* A16 = (f16*)ws;
  f16* coA = (f16*)ws;  // alias: A16 dead after GEMM1
  f16* coB = (f16*)(ws + 8388608);
  f16* w2h = (f16*)(ws + 52428800);
  f16* c_h = (f16*)(ws + 52428800 + 1638400);
  f16* s_h = (f16*)(ws + 52428800 + 1638400 + 33554432);
  f16* w2o = (f16*)(ws + 52428800 + 1638400 + 33554432 + 33554432);

  // merged conversions: spikes->A16 and weights->w2h/w2o in one dispatch
  conv_all<<<16256, 256, 0, stream>>>(spikes, w_hidden, w_out, A16, w2h, w2o);

  // GEMM1: c_h[32768][512] (f16) = A16[32768][800] * w2h[512][800hi|800lo]^T
  gemm_f16<f16, 512, 800, 1600, 12, true, 800, 0, true>
      <<<1024, 256, 0, stream>>>(A16, w2h, c_h);

  lif_scan<<<256, 256, 0, stream>>>(c_h, s_h);

  // GEMM2: co{A,B}[32768][128] (f16) = s_h[32768][512] * w2o[128][512]^T, K-split 2x256
  gemm_f16<f16, 128, 512, 512, 4, false, 0, 256, false>
      <<<dim3(2, 256), 256, 0, stream>>>(s_h, w2o, coA);

  li_scan_seg<<<256, 256, 0, stream>>>(coA, coB, out);
}